// Round 7
// baseline (4315.909 us; speedup 1.0000x reference)
//
#include <hip/hip_runtime.h>

#define T_SEQ 512
#define BATCH 64
#define IN_F  1024
#define HID_F 1024
#define G4    4096

typedef __bf16 bf16x8 __attribute__((ext_vector_type(8)));
typedef float  f32x4  __attribute__((ext_vector_type(4)));
typedef unsigned short u16;
typedef unsigned int   u32;
typedef unsigned long long u64;

__device__ __forceinline__ u16 f2bf(float x) {
    u32 u = __builtin_bit_cast(u32, x);
    u = (u + 0x7FFFu + ((u >> 16) & 1u)) >> 16;   // RTNE
    return (u16)u;
}

__device__ __forceinline__ float sigf(float x) {
    return 1.0f / (1.0f + __expf(-x));
}
__device__ __forceinline__ float tanh_fast(float x) {
    float e = __expf(-2.0f * fabsf(x));
    float t = (1.0f - e) / (1.0f + e);
    return x < 0.0f ? -t : t;
}

// ---------------- fp32 -> bf16 cast ----------------
__global__ void cast_bf16_k(const float* __restrict__ in, u16* __restrict__ out, long n4) {
    long i = (long)blockIdx.x * blockDim.x + threadIdx.x;
    long stride = (long)gridDim.x * blockDim.x;
    for (; i < n4; i += stride) {
        float4 v = ((const float4*)in)[i];
        ushort4 o = make_ushort4(f2bf(v.x), f2bf(v.y), f2bf(v.z), f2bf(v.w));
        ((ushort4*)out)[i] = o;
    }
}

// ---------------- xg = x @ W_ih^T + (b_ih+b_hh), output transposed [t][4096][64] ----------------
__global__ __launch_bounds__(256) void xg_gemm_k(
    const u16* __restrict__ A, const u16* __restrict__ Bm,
    const float* __restrict__ bih, const float* __restrict__ bhh,
    float* __restrict__ out)
{
    __shared__ __align__(16) u16 As[128][40];
    __shared__ __align__(16) u16 Bs[128][40];

    const int tid  = threadIdx.x;
    const int bg   = blockIdx.y * 128;
    const int btb  = blockIdx.x * 128;
    const int lane = tid & 63;
    const int wid  = tid >> 6;
    const int wr   = wid >> 1;
    const int wc   = wid & 1;
    const int lrow = lane & 15;
    const int lq   = lane >> 4;

    f32x4 acc[4][4];
    #pragma unroll
    for (int i = 0; i < 4; ++i)
        #pragma unroll
        for (int j = 0; j < 4; ++j)
            acc[i][j] = (f32x4){0.f, 0.f, 0.f, 0.f};

    for (int k0 = 0; k0 < 1024; k0 += 32) {
        #pragma unroll
        for (int s = 0; s < 2; ++s) {
            int u   = tid + s * 256;
            int row = u >> 2;
            int ko  = (u & 3) * 8;
            *(uint4*)&As[row][ko] = *(const uint4*)&A [(size_t)(bg  + row) * 1024 + k0 + ko];
            *(uint4*)&Bs[row][ko] = *(const uint4*)&Bm[(size_t)(btb + row) * 1024 + k0 + ko];
        }
        __syncthreads();

        bf16x8 af[4], bf[4];
        #pragma unroll
        for (int i = 0; i < 4; ++i) {
            af[i] = *(const bf16x8*)&As[wr * 64 + i * 16 + lrow][lq * 8];
            bf[i] = *(const bf16x8*)&Bs[wc * 64 + i * 16 + lrow][lq * 8];
        }
        #pragma unroll
        for (int mi = 0; mi < 4; ++mi)
            #pragma unroll
            for (int ni = 0; ni < 4; ++ni)
                acc[mi][ni] = __builtin_amdgcn_mfma_f32_16x16x32_bf16(af[mi], bf[ni], acc[mi][ni], 0, 0, 0);
        __syncthreads();
    }

    float bsum[4][4];
    #pragma unroll
    for (int mi = 0; mi < 4; ++mi)
        #pragma unroll
        for (int r = 0; r < 4; ++r) {
            int g = bg + wr * 64 + mi * 16 + lq * 4 + r;
            bsum[mi][r] = bih[g] + bhh[g];
        }

    #pragma unroll
    for (int mi = 0; mi < 4; ++mi)
        #pragma unroll
        for (int ni = 0; ni < 4; ++ni)
            #pragma unroll
            for (int r = 0; r < 4; ++r) {
                int g  = bg + wr * 64 + mi * 16 + lq * 4 + r;
                int tb = btb + wc * 64 + ni * 16 + lrow;
                int t  = tb >> 6;
                int b  = tb & 63;
                out[((size_t)t * G4 + g) * 64 + b] = acc[mi][ni][r] + bsum[mi][r];
            }
}

// ---------------- persistent LSTM recurrence, stamped-cell sync ----------------
// 256 WGs x 256 threads. WG (bid>>2) owns hidden units j0..j0+15, (bid&3) owns
// batch quadrant b0..b0+15 (4 independent domains of 64 WGs).
// h exchanged as stamped 8B cells: [15:0]=h(2p) bf16, [31:16]=h(2p+1) bf16,
// [63:32]=stamp (= step index of the h vector). Producer: ONE relaxed
// agent-scope u64 store per cell, no ack, no slot, no fence — the store IS the
// signal. Consumer: staging loads ARE the poll (re-load cells whose stamp !=
// expected). Parity-2 ring is race-free: overwriting h(t-1) requires having
// consumed all of h(t), which proves all peers finished reading h(t-1).
// Buffers: u64 [64 rows][512 cells], parity per step. Stamps reset by memset
// once per kernel_launch (t0==0); stamp for step g is exactly g.
__global__ __launch_bounds__(256, 1) void lstm_seq_k(
    const u16* __restrict__ Whh,     // bf16 [4096][1024]
    u64* __restrict__ h0c,           // u64 [64][512], parity-0 stamped cells
    u64* __restrict__ h1c,           // parity-1
    float* __restrict__ cT,          // f32 [1024][64]
    const float* __restrict__ xgT,   // f32 [tc][4096][64] (chunk-local)
    float* __restrict__ y,           // f32 [T][64][1024]
    int t0, int tc)
{
    __shared__ __align__(16) u16 hs[16 * 1024];   // 32 KB, XOR-swizzled 16B units
    __shared__ float Gs[16][17];

    const int tid  = threadIdx.x;
    const int lane = tid & 63;
    const int w    = tid >> 6;
    const int lq   = lane >> 4;
    const int lr   = lane & 15;
    const int bid  = blockIdx.x;
    const int jwg  = bid >> 2;         // 0..63
    const int quad = bid & 3;
    const int j0   = jwg * 16;
    const int b0   = quad * 16;

    // ---- load A fragments once: row m=lr -> (jj=m>>2, gate=m&3) ----
    const int gate = lr & 3;
    const int jja  = lr >> 2;
    const size_t woff = (size_t)(gate * 1024 + j0 + w * 4 + jja) * 1024 + lq * 8;
    bf16x8 af[32];
    #pragma unroll
    for (int kk = 0; kk < 32; ++kk)
        af[kk] = *(const bf16x8*)&Whh[woff + (size_t)kk * 32];

    const int jme = j0 + w * 4 + lq;   // this lane's hidden unit
    const int bme = b0 + lr;           // this lane's batch
    float c = (t0 == 0) ? 0.0f : cT[(size_t)jme * 64 + bme];
    const int swl = lr & 7;
    const int cellme = (j0 + 4 * w + lq) >> 1;   // cell this lane stores (even lq only)

    for (int tt = 0; tt < tc; ++tt) {
        const int gstep = t0 + tt;
        const u64* __restrict__ hin = (gstep & 1) ? h1c : h0c;
        u64* __restrict__ hout      = (gstep & 1) ? h0c : h1c;
        const float* __restrict__ xg = xgT + (size_t)tt * (G4 * BATCH);
        const u32 stampexp = (u32)gstep;

        // xg loads first (independent, cached) — overlap with cell polling
        float xgv[4];
        #pragma unroll
        for (int g = 0; g < 4; ++g)
            xgv[g] = xg[(size_t)(g * 1024 + jme) * 64 + bme];

        // staging loads ARE the poll: 8192 cells / 256 thr = 32 cells/thread
        u32 pv[32];
        #pragma unroll
        for (int ph = 0; ph < 2; ++ph) {
            u64 v[16];
            #pragma unroll
            for (int s = 0; s < 16; ++s) {
                int g = tid + (ph * 16 + s) * 256;
                v[s] = __hip_atomic_load(&hin[(size_t)(b0 + (g >> 9)) * 512 + (g & 511)],
                                         __ATOMIC_RELAXED, __HIP_MEMORY_SCOPE_AGENT);
            }
            #pragma unroll
            for (int s = 0; s < 16; ++s) {
                int g = tid + (ph * 16 + s) * 256;
                const u64* p = &hin[(size_t)(b0 + (g >> 9)) * 512 + (g & 511)];
                while ((u32)(v[s] >> 32) != stampexp) {
                    __builtin_amdgcn_s_sleep(1);
                    v[s] = __hip_atomic_load(p, __ATOMIC_RELAXED, __HIP_MEMORY_SCOPE_AGENT);
                }
                pv[ph * 16 + s] = (u32)v[s];
            }
        }
        // unpack pairs into XOR-swizzled LDS (same layout the MFMA reads)
        #pragma unroll
        for (int s2 = 0; s2 < 32; ++s2) {
            int g = tid + s2 * 256;
            int row = g >> 9, p = g & 511;
            int u = p >> 2;
            *(u32*)((char*)hs + row * 2048 + ((u ^ (row & 7)) * 16) + (p & 3) * 4) = pv[s2];
        }
        __syncthreads();

        f32x4 acc[4];
        #pragma unroll
        for (int q = 0; q < 4; ++q) acc[q] = (f32x4){0.f, 0.f, 0.f, 0.f};
        #pragma unroll
        for (int kk = 0; kk < 32; ++kk) {
            bf16x8 bf = *(const bf16x8*)&hs[lr * 1024 + (((lq + 4 * kk) ^ swl) * 8)];
            acc[kk & 3] = __builtin_amdgcn_mfma_f32_16x16x32_bf16(af[kk], bf, acc[kk & 3], 0, 0, 0);
        }
        f32x4 g4 = (acc[0] + acc[1]) + (acc[2] + acc[3]);

        // lane-local gates: reg r = gate r for (jme, bme)
        float cn = sigf(g4[1] + xgv[1]) * c + sigf(g4[0] + xgv[0]) * tanh_fast(g4[2] + xgv[2]);
        float hn = sigf(g4[3] + xgv[3]) * tanh_fast(cn);
        c = cn;

        // publish h(t+1): stamped cell (2 j-values + stamp), fire-and-forget
        float hp = __shfl(hn, (lane + 16) & 63);   // partner j+1 for even lq
        if ((lq & 1) == 0) {
            u64 cell = (u64)f2bf(hn) | ((u64)f2bf(hp) << 16) | ((u64)(u32)(gstep + 1) << 32);
            __hip_atomic_store(&hout[(size_t)(b0 + lr) * 512 + cellme], cell,
                               __ATOMIC_RELAXED, __HIP_MEMORY_SCOPE_AGENT);
        }

        // y store (off the critical path), coalesced via LDS routing
        Gs[w * 4 + lq][lr] = hn;
        __syncthreads();
        int bb = tid >> 4, jj = tid & 15;
        float* yt = y + (size_t)gstep * (BATCH * HID_F);
        yt[(size_t)(b0 + bb) * 1024 + j0 + jj] = Gs[jj][bb];
    }
    cT[(size_t)jme * 64 + bme] = c;
}

extern "C" void kernel_launch(void* const* d_in, const int* in_sizes, int n_in,
                              void* d_out, int out_size, void* d_ws, size_t ws_size,
                              hipStream_t stream) {
    const float* x    = (const float*)d_in[0];
    const float* Wih  = (const float*)d_in[1];
    const float* Whh  = (const float*)d_in[2];
    const float* bih  = (const float*)d_in[3];
    const float* bhh  = (const float*)d_in[4];
    float* y = (float*)d_out;

    char* ws = (char*)d_ws;
    size_t off = 0;
    auto alloc = [&](size_t bytes) { size_t p = off; off += (bytes + 255) & ~(size_t)255; return p; };

    u16* xb    = (u16*)(ws + alloc((size_t)T_SEQ * BATCH * IN_F * 2));  // 64 MB
    u16* wihb  = (u16*)(ws + alloc((size_t)G4 * IN_F * 2));             // 8 MB
    u16* whhb  = (u16*)(ws + alloc((size_t)G4 * HID_F * 2));            // 8 MB
    u64* hbuf0 = (u64*)(ws + alloc((size_t)BATCH * 512 * 8));           // 256 KB stamped cells
    u64* hbuf1 = (u64*)(ws + alloc((size_t)BATCH * 512 * 8));           // 256 KB
    float* cT  = (float*)(ws + alloc((size_t)HID_F * BATCH * 4));

    size_t slot_bytes = (size_t)G4 * BATCH * 4;   // 1 MB per timestep
    size_t remain = ws_size > off ? ws_size - off : 0;
    long ringT = (long)(remain / slot_bytes);
    if (ringT > T_SEQ) ringT = T_SEQ;
    ringT &= ~1L;
    if (ringT < 2) ringT = 2;
    float* xgT = (float*)(ws + alloc((size_t)ringT * slot_bytes));

    cast_bf16_k<<<2048, 256, 0, stream>>>(x,   xb,   (long)T_SEQ * BATCH * IN_F / 4);
    cast_bf16_k<<<512,  256, 0, stream>>>(Wih, wihb, (long)G4 * IN_F / 4);
    cast_bf16_k<<<512,  256, 0, stream>>>(Whh, whhb, (long)G4 * HID_F / 4);

    // zero both parity buffers: data h(0)=0 AND stamps=0 (stamp for step 0)
    hipMemsetAsync(hbuf0, 0, (size_t)BATCH * 512 * 8 * 2, stream);

    for (long t0 = 0; t0 < T_SEQ; t0 += ringT) {
        long tc = T_SEQ - t0 < ringT ? T_SEQ - t0 : ringT;
        dim3 ggrid((unsigned)(tc * BATCH / 128), G4 / 128);
        xg_gemm_k<<<ggrid, 256, 0, stream>>>(wihb, xb + (size_t)t0 * BATCH * IN_F, bih, bhh, xgT);
        lstm_seq_k<<<256, 256, 0, stream>>>(whhb, hbuf0, hbuf1, cT, xgT, y, (int)t0, (int)tc);
    }
}

// Round 8
// 4229.187 us; speedup vs baseline: 1.0205x; 1.0205x over previous
//
#include <hip/hip_runtime.h>

#define T_SEQ 512
#define BATCH 64
#define IN_F  1024
#define HID_F 1024
#define G4    4096

typedef __bf16 bf16x8 __attribute__((ext_vector_type(8)));
typedef float  f32x4  __attribute__((ext_vector_type(4)));
typedef unsigned short u16;
typedef unsigned int   u32;
typedef unsigned long long u64;

__device__ __forceinline__ u16 f2bf(float x) {
    u32 u = __builtin_bit_cast(u32, x);
    u = (u + 0x7FFFu + ((u >> 16) & 1u)) >> 16;   // RTNE
    return (u16)u;
}

__device__ __forceinline__ float sigf(float x) {
    return 1.0f / (1.0f + __expf(-x));
}
__device__ __forceinline__ float tanh_fast(float x) {
    float e = __expf(-2.0f * fabsf(x));
    float t = (1.0f - e) / (1.0f + e);
    return x < 0.0f ? -t : t;
}

// ---------------- fp32 -> bf16 cast ----------------
__global__ void cast_bf16_k(const float* __restrict__ in, u16* __restrict__ out, long n4) {
    long i = (long)blockIdx.x * blockDim.x + threadIdx.x;
    long stride = (long)gridDim.x * blockDim.x;
    for (; i < n4; i += stride) {
        float4 v = ((const float4*)in)[i];
        ushort4 o = make_ushort4(f2bf(v.x), f2bf(v.y), f2bf(v.z), f2bf(v.w));
        ((ushort4*)out)[i] = o;
    }
}

// ---------------- persistent LSTM, fused x-GEMM, round-5 sync ----------------
// 256 WGs x 256 threads, 1 WG/CU. WG (bid>>2) owns j0..j0+15, (bid&3) owns batch
// quadrant b0..b0+15 (4 independent sync domains of 64 WGs).
// Per step, gates = W_hh@h(t) + W_ih@x(t) + bias computed in ONE interleaved
// MFMA loop (64 MFMAs): W_hh fragments in registers (af[32], loaded once),
// W_ih rows in LDS (128 KB, staged once, XOR-swizzled), x(t) B-fragments
// streamed from global through an 8-deep register pipeline (cached loads —
// x is read-only, no coherence hazard). h exchange + slot protocol = round 5
// verbatim (relaxed agent-scope write-through/bypass, no fences).
// LDS: ws 128KB + hs 32KB = 160 KiB exactly; y-routing Gs overlays dead hs.
__global__ __launch_bounds__(256, 1) void lstm_seq_k(
    const u16* __restrict__ Whh,     // bf16 [4096][1024]
    const u16* __restrict__ Wih,     // bf16 [4096][1024]
    const u16* __restrict__ xb,      // bf16 [T*B][1024]
    u64* __restrict__ h0b,           // u64 [64][256], parity-0
    u64* __restrict__ h1b,           // parity-1
    const float* __restrict__ bih, const float* __restrict__ bhh,
    float* __restrict__ y,           // f32 [T][64][1024]
    unsigned* __restrict__ slots)    // [4][64] u32, zeroed per launch
{
    __shared__ __align__(16) u16 ws[64 * 1024];   // 128 KB W_ih rows, swizzled
    __shared__ __align__(16) u16 hs[16 * 1024];   // 32 KB h tile, swizzled
    float* Gsp = (float*)hs;                      // overlay [16][17] after MFMA

    const int tid  = threadIdx.x;
    const int lane = tid & 63;
    const int w    = tid >> 6;
    const int lq   = lane >> 4;
    const int lr   = lane & 15;
    const int bid  = blockIdx.x;
    const int jwg  = bid >> 2;         // 0..63
    const int quad = bid & 3;
    const int j0   = jwg * 16;
    const int b0   = quad * 16;
    unsigned* qslots = slots + quad * 64;

    // ---- W_hh fragments in registers: row m=lr -> (jj=m>>2, gate=m&3) ----
    const int gate = lr & 3;
    const int jja  = lr >> 2;
    const size_t woff = (size_t)(gate * 1024 + j0 + w * 4 + jja) * 1024 + lq * 8;
    bf16x8 af[32];
    #pragma unroll
    for (int kk = 0; kk < 32; ++kk)
        af[kk] = *(const bf16x8*)&Whh[woff + (size_t)kk * 32];

    // ---- stage this WG's 64 W_ih rows into LDS, swizzled (same map as af) ----
    #pragma unroll
    for (int s = 0; s < 32; ++s) {
        int u   = tid + s * 256;          // 16B-unit 0..8191
        int row = u >> 7;                 // 0..63
        int cu  = u & 127;
        int grow = (row & 3) * 1024 + j0 + (row >> 4) * 4 + ((row >> 2) & 3);
        *(uint4*)&ws[row * 1024 + ((cu ^ (row & 7)) * 8)] =
            *(const uint4*)&Wih[(size_t)grow * 1024 + cu * 8];
    }

    const int jme = j0 + w * 4 + lq;   // this lane's hidden unit
    const int bme = b0 + lr;           // this lane's batch
    float c = 0.0f;
    const int swl = lr & 7;
    const int wsrow = (w * 16 + lr) * 1024;

    float bs[4];
    #pragma unroll
    for (int g = 0; g < 4; ++g)
        bs[g] = bih[g * 1024 + jme] + bhh[g * 1024 + jme];

    __syncthreads();   // ws staged

    for (int tt = 0; tt < T_SEQ; ++tt) {
        const u64* __restrict__ hin = (tt & 1) ? h1b : h0b;
        u64* __restrict__ hout      = (tt & 1) ? h0b : h1b;

        if (tt > 0) {
            const unsigned stamp = (unsigned)tt;
            if (w == 0) {
                while (true) {
                    unsigned v = __hip_atomic_load(&qslots[lane], __ATOMIC_RELAXED, __HIP_MEMORY_SCOPE_AGENT);
                    if (__all((int)(v >= stamp))) break;
                    __builtin_amdgcn_s_sleep(4);
                }
            }
            __syncthreads();
            asm volatile("" ::: "memory");
        }

        // stage h tile [b0..b0+15][1024] -> LDS via bypassing u64 loads,
        // XOR-swizzled 16B units. row stride = 256 u64.
        u64 hv[16];
        #pragma unroll
        for (int s = 0; s < 8; ++s) {
            int g = tid + s * 256;            // 16B-unit index 0..2047
            int row = g >> 7, col = g & 127;
            const u64* p = hin + (size_t)(b0 + row) * 256 + col * 2;
            hv[2 * s]     = __hip_atomic_load(p,     __ATOMIC_RELAXED, __HIP_MEMORY_SCOPE_AGENT);
            hv[2 * s + 1] = __hip_atomic_load(p + 1, __ATOMIC_RELAXED, __HIP_MEMORY_SCOPE_AGENT);
        }
        #pragma unroll
        for (int s = 0; s < 8; ++s) {
            int g = tid + s * 256;
            int row = g >> 7, col = g & 127;
            uint4 q;
            q.x = (u32)hv[2 * s];     q.y = (u32)(hv[2 * s] >> 32);
            q.z = (u32)hv[2 * s + 1]; q.w = (u32)(hv[2 * s + 1] >> 32);
            *(uint4*)&hs[row * 1024 + ((col ^ (row & 7)) * 8)] = q;
        }
        __syncthreads();

        // interleaved MFMA: gates = W_hh@h + W_ih@x, 8-deep x stream
        const u16* __restrict__ xrow = xb + ((size_t)tt * BATCH + b0 + lr) * 1024 + lq * 8;
        bf16x8 bx[8];
        #pragma unroll
        for (int p = 0; p < 8; ++p)
            bx[p] = *(const bf16x8*)(xrow + p * 32);

        f32x4 acc[4];
        #pragma unroll
        for (int q = 0; q < 4; ++q) acc[q] = (f32x4){0.f, 0.f, 0.f, 0.f};
        #pragma unroll
        for (int kk = 0; kk < 32; ++kk) {
            bf16x8 bh = *(const bf16x8*)&hs[lr * 1024 + (((lq + 4 * kk) ^ swl) * 8)];
            bf16x8 ax = *(const bf16x8*)&ws[wsrow + (((lq + 4 * kk) ^ swl) * 8)];
            acc[kk & 3] = __builtin_amdgcn_mfma_f32_16x16x32_bf16(af[kk], bh, acc[kk & 3], 0, 0, 0);
            acc[kk & 3] = __builtin_amdgcn_mfma_f32_16x16x32_bf16(ax, bx[kk & 7], acc[kk & 3], 0, 0, 0);
            if (kk < 24)
                bx[kk & 7] = *(const bf16x8*)(xrow + (kk + 8) * 32);
        }
        f32x4 g4 = (acc[0] + acc[1]) + (acc[2] + acc[3]);

        // lane-local gates: reg r = gate r for (jme, bme)
        float cn = sigf(g4[1] + bs[1]) * c + sigf(g4[0] + bs[0]) * tanh_fast(g4[2] + bs[2]);
        float hn = sigf(g4[3] + bs[3]) * tanh_fast(cn);
        c = cn;

        // publish h(t+1): pack 4 j-values per b-row into one u64, fire-and-forget
        float h1 = __shfl(hn, lr + 16);
        float h2 = __shfl(hn, lr + 32);
        float h3 = __shfl(hn, lr + 48);
        if (lq == 0) {
            u64 pv = (u64)f2bf(hn) | ((u64)f2bf(h1) << 16) |
                     ((u64)f2bf(h2) << 32) | ((u64)f2bf(h3) << 48);
            __hip_atomic_store(hout + (size_t)(b0 + lr) * 256 + (j0 >> 2) + w, pv,
                               __ATOMIC_RELAXED, __HIP_MEMORY_SCOPE_AGENT);
        }

        __syncthreads();                 // all hs/ws MFMA reads done -> Gs overlay safe
        Gsp[(w * 4 + lq) * 17 + lr] = hn;

        asm volatile("s_waitcnt vmcnt(0)" ::: "memory");   // h stores acked
        __syncthreads();                                    // WG drained + Gs ready
        if (tid == 0)
            __hip_atomic_store(&qslots[jwg], (unsigned)(tt + 1),
                               __ATOMIC_RELAXED, __HIP_MEMORY_SCOPE_AGENT);

        // y store (off the critical path), coalesced via Gs routing
        int bb = tid >> 4, jj = tid & 15;
        float* yt = y + (size_t)tt * (BATCH * HID_F);
        yt[(size_t)(b0 + bb) * 1024 + j0 + jj] = Gsp[jj * 17 + bb];
    }
}

extern "C" void kernel_launch(void* const* d_in, const int* in_sizes, int n_in,
                              void* d_out, int out_size, void* d_ws, size_t ws_size,
                              hipStream_t stream) {
    const float* x    = (const float*)d_in[0];
    const float* Wih  = (const float*)d_in[1];
    const float* Whh  = (const float*)d_in[2];
    const float* bih  = (const float*)d_in[3];
    const float* bhh  = (const float*)d_in[4];
    float* y = (float*)d_out;

    char* ws = (char*)d_ws;
    size_t off = 0;
    auto alloc = [&](size_t bytes) { size_t p = off; off += (bytes + 255) & ~(size_t)255; return p; };

    unsigned* slots = (unsigned*)(ws + alloc(4 * 64 * 4));              // [4][64]
    u16* xb    = (u16*)(ws + alloc((size_t)T_SEQ * BATCH * IN_F * 2));  // 64 MB
    u16* wihb  = (u16*)(ws + alloc((size_t)G4 * IN_F * 2));             // 8 MB
    u16* whhb  = (u16*)(ws + alloc((size_t)G4 * HID_F * 2));            // 8 MB
    u64* hbuf0 = (u64*)(ws + alloc((size_t)BATCH * 256 * 8));           // 128 KB
    u64* hbuf1 = (u64*)(ws + alloc((size_t)BATCH * 256 * 8));           // 128 KB

    cast_bf16_k<<<2048, 256, 0, stream>>>(x,   xb,   (long)T_SEQ * BATCH * IN_F / 4);
    cast_bf16_k<<<512,  256, 0, stream>>>(Wih, wihb, (long)G4 * IN_F / 4);
    cast_bf16_k<<<512,  256, 0, stream>>>(Whh, whhb, (long)G4 * HID_F / 4);

    hipMemsetAsync(slots, 0, 4 * 64 * 4, stream);
    hipMemsetAsync(hbuf0, 0, (size_t)BATCH * 256 * 8, stream);   // h(0) = 0

    lstm_seq_k<<<256, 256, 0, stream>>>(whhb, wihb, xb, hbuf0, hbuf1, bih, bhh, y, slots);
}

// Round 9
// 3353.313 us; speedup vs baseline: 1.2871x; 1.2612x over previous
//
#include <hip/hip_runtime.h>

#define T_SEQ 512
#define BATCH 64
#define IN_F  1024
#define HID_F 1024
#define G4    4096

typedef __bf16 bf16x8 __attribute__((ext_vector_type(8)));
typedef float  f32x4  __attribute__((ext_vector_type(4)));
typedef unsigned short u16;
typedef unsigned int   u32;
typedef unsigned long long u64;

__device__ __forceinline__ u16 f2bf(float x) {
    u32 u = __builtin_bit_cast(u32, x);
    u = (u + 0x7FFFu + ((u >> 16) & 1u)) >> 16;   // RTNE
    return (u16)u;
}

__device__ __forceinline__ float sigf(float x) {
    return 1.0f / (1.0f + __expf(-x));
}
__device__ __forceinline__ float tanh_fast(float x) {
    float e = __expf(-2.0f * fabsf(x));
    float t = (1.0f - e) / (1.0f + e);
    return x < 0.0f ? -t : t;
}

// ---------------- fp32 -> bf16 cast ----------------
__global__ void cast_bf16_k(const float* __restrict__ in, u16* __restrict__ out, long n4) {
    long i = (long)blockIdx.x * blockDim.x + threadIdx.x;
    long stride = (long)gridDim.x * blockDim.x;
    for (; i < n4; i += stride) {
        float4 v = ((const float4*)in)[i];
        ushort4 o = make_ushort4(f2bf(v.x), f2bf(v.y), f2bf(v.z), f2bf(v.w));
        ((ushort4*)out)[i] = o;
    }
}

// ---------------- persistent LSTM, fused x-GEMM, latency-hidden schedule ----------------
// 256 WGs x 256 threads, 1 WG/CU. WG (bid>>2) owns j0..j0+15, (bid&3) owns batch
// quadrant b0..b0+15 (4 independent sync domains of 64 WGs).
// Per step: gates = W_hh@h(t) + W_ih@x(t) + bias.
//   phase 1 (pre-poll): issue 16/32 x B-fragments (x independent of h -> its
//            latency overlaps the slot wait itself)
//   phase 2: poll slots (round-5 protocol verbatim)
//   phase 3: issue h-tile global loads (bypassing u64), then immediately
//   phase 4: loop A - 32 MFMAs of W_ih(LDS)@x(reg), rotating in x chunks 16..31
//            (h loads fly under ~550cyc of MFMA+LDS work)
//   phase 5: unpack h -> LDS (swizzled), sync
//   phase 6: loop B - 32 MFMAs of W_hh(reg)@h(LDS)
//   phase 7: gates, publish h(t+1) (write-through), vmcnt ack, signal slot, y store
// LDS: ws 128KB (W_ih, staged once) + hs 32KB = 160 KiB; Gs overlays hs tail.
__global__ __launch_bounds__(256, 1) void lstm_seq_k(
    const u16* __restrict__ Whh,     // bf16 [4096][1024]
    const u16* __restrict__ Wih,     // bf16 [4096][1024]
    const u16* __restrict__ xb,      // bf16 [T*B][1024]
    u64* __restrict__ h0b,           // u64 [64][256], parity-0
    u64* __restrict__ h1b,           // parity-1
    const float* __restrict__ bih, const float* __restrict__ bhh,
    float* __restrict__ y,           // f32 [T][64][1024]
    unsigned* __restrict__ slots)    // [4][64] u32, zeroed per launch
{
    __shared__ __align__(16) u16 ws[64 * 1024];   // 128 KB W_ih rows, swizzled
    __shared__ __align__(16) u16 hs[16 * 1024];   // 32 KB h tile, swizzled
    float* Gsp = (float*)hs;                      // overlay [16][17] after loop B

    const int tid  = threadIdx.x;
    const int lane = tid & 63;
    const int w    = tid >> 6;
    const int lq   = lane >> 4;
    const int lr   = lane & 15;
    const int bid  = blockIdx.x;
    const int jwg  = bid >> 2;         // 0..63
    const int quad = bid & 3;
    const int j0   = jwg * 16;
    const int b0   = quad * 16;
    unsigned* qslots = slots + quad * 64;

    // ---- W_hh fragments in registers: row m=lr -> (jj=m>>2, gate=m&3) ----
    const int gate = lr & 3;
    const int jja  = lr >> 2;
    const size_t woff = (size_t)(gate * 1024 + j0 + w * 4 + jja) * 1024 + lq * 8;
    bf16x8 af[32];
    #pragma unroll
    for (int kk = 0; kk < 32; ++kk)
        af[kk] = *(const bf16x8*)&Whh[woff + (size_t)kk * 32];

    // ---- stage this WG's 64 W_ih rows into LDS, swizzled (same map as af) ----
    #pragma unroll
    for (int s = 0; s < 32; ++s) {
        int u   = tid + s * 256;          // 16B-unit 0..8191
        int row = u >> 7;                 // 0..63
        int cu  = u & 127;
        int grow = (row & 3) * 1024 + j0 + (row >> 4) * 4 + ((row >> 2) & 3);
        *(uint4*)&ws[row * 1024 + ((cu ^ (row & 7)) * 8)] =
            *(const uint4*)&Wih[(size_t)grow * 1024 + cu * 8];
    }

    const int jme = j0 + w * 4 + lq;   // this lane's hidden unit
    const int bme = b0 + lr;           // this lane's batch (doc only)
    (void)bme;
    float c = 0.0f;
    const int swl = lr & 7;
    const int wsrow = (w * 16 + lr) * 1024;

    float bs[4];
    #pragma unroll
    for (int g = 0; g < 4; ++g)
        bs[g] = bih[g * 1024 + jme] + bhh[g * 1024 + jme];

    __syncthreads();   // ws staged

    for (int tt = 0; tt < T_SEQ; ++tt) {
        const u64* __restrict__ hin = (tt & 1) ? h1b : h0b;
        u64* __restrict__ hout      = (tt & 1) ? h0b : h1b;

        // ---- phase 1: pre-poll x prefetch (chunks 0..15, 256B/lane) ----
        const u16* __restrict__ xrow = xb + ((size_t)tt * BATCH + b0 + lr) * 1024 + lq * 8;
        bf16x8 bx[16];
        #pragma unroll
        for (int p = 0; p < 16; ++p)
            bx[p] = *(const bf16x8*)(xrow + p * 32);

        // ---- phase 2: poll (round-5 protocol) ----
        if (tt > 0) {
            const unsigned stamp = (unsigned)tt;
            if (w == 0) {
                while (true) {
                    unsigned v = __hip_atomic_load(&qslots[lane], __ATOMIC_RELAXED, __HIP_MEMORY_SCOPE_AGENT);
                    if (__all((int)(v >= stamp))) break;
                    __builtin_amdgcn_s_sleep(4);
                }
            }
            __syncthreads();
            asm volatile("" ::: "memory");
        }

        // ---- phase 3: issue h-tile loads (bypassing u64), latency hidden by loop A ----
        u64 hv[16];
        #pragma unroll
        for (int s = 0; s < 8; ++s) {
            int g = tid + s * 256;            // 16B-unit index 0..2047
            int row = g >> 7, col = g & 127;
            const u64* p = hin + (size_t)(b0 + row) * 256 + col * 2;
            hv[2 * s]     = __hip_atomic_load(p,     __ATOMIC_RELAXED, __HIP_MEMORY_SCOPE_AGENT);
            hv[2 * s + 1] = __hip_atomic_load(p + 1, __ATOMIC_RELAXED, __HIP_MEMORY_SCOPE_AGENT);
        }

        // ---- phase 4: loop A — W_ih @ x (LDS x reg), rotate in x chunks 16..31 ----
        f32x4 acc[4];
        #pragma unroll
        for (int q = 0; q < 4; ++q) acc[q] = (f32x4){0.f, 0.f, 0.f, 0.f};
        #pragma unroll
        for (int kk = 0; kk < 32; ++kk) {
            bf16x8 ax = *(const bf16x8*)&ws[wsrow + (((lq + 4 * kk) ^ swl) * 8)];
            acc[kk & 3] = __builtin_amdgcn_mfma_f32_16x16x32_bf16(ax, bx[kk & 15], acc[kk & 3], 0, 0, 0);
            if (kk < 16)
                bx[kk] = *(const bf16x8*)(xrow + (kk + 16) * 32);
        }

        // ---- phase 5: unpack h -> LDS (XOR-swizzled 16B units) ----
        #pragma unroll
        for (int s = 0; s < 8; ++s) {
            int g = tid + s * 256;
            int row = g >> 7, col = g & 127;
            uint4 q;
            q.x = (u32)hv[2 * s];     q.y = (u32)(hv[2 * s] >> 32);
            q.z = (u32)hv[2 * s + 1]; q.w = (u32)(hv[2 * s + 1] >> 32);
            *(uint4*)&hs[row * 1024 + ((col ^ (row & 7)) * 8)] = q;
        }
        __syncthreads();

        // ---- phase 6: loop B — W_hh @ h (reg x LDS) ----
        #pragma unroll
        for (int kk = 0; kk < 32; ++kk) {
            bf16x8 bh = *(const bf16x8*)&hs[lr * 1024 + (((lq + 4 * kk) ^ swl) * 8)];
            acc[kk & 3] = __builtin_amdgcn_mfma_f32_16x16x32_bf16(af[kk], bh, acc[kk & 3], 0, 0, 0);
        }
        f32x4 g4 = (acc[0] + acc[1]) + (acc[2] + acc[3]);

        // ---- phase 7: gates (lane-local), publish, signal, y ----
        float cn = sigf(g4[1] + bs[1]) * c + sigf(g4[0] + bs[0]) * tanh_fast(g4[2] + bs[2]);
        float hn = sigf(g4[3] + bs[3]) * tanh_fast(cn);
        c = cn;

        float h1 = __shfl(hn, lr + 16);
        float h2 = __shfl(hn, lr + 32);
        float h3 = __shfl(hn, lr + 48);
        if (lq == 0) {
            u64 pv = (u64)f2bf(hn) | ((u64)f2bf(h1) << 16) |
                     ((u64)f2bf(h2) << 32) | ((u64)f2bf(h3) << 48);
            __hip_atomic_store(hout + (size_t)(b0 + lr) * 256 + (j0 >> 2) + w, pv,
                               __ATOMIC_RELAXED, __HIP_MEMORY_SCOPE_AGENT);
        }

        __syncthreads();                 // all hs MFMA reads done -> Gs overlay safe
        Gsp[(w * 4 + lq) * 17 + lr] = hn;

        asm volatile("s_waitcnt vmcnt(0)" ::: "memory");   // h stores acked
        __syncthreads();                                    // WG drained + Gs ready
        if (tid == 0)
            __hip_atomic_store(&qslots[jwg], (unsigned)(tt + 1),
                               __ATOMIC_RELAXED, __HIP_MEMORY_SCOPE_AGENT);

        // y store (off the critical path), coalesced via Gs routing
        int bb = tid >> 4, jj = tid & 15;
        float* yt = y + (size_t)tt * (BATCH * HID_F);
        yt[(size_t)(b0 + bb) * 1024 + j0 + jj] = Gsp[jj * 17 + bb];
    }
}

extern "C" void kernel_launch(void* const* d_in, const int* in_sizes, int n_in,
                              void* d_out, int out_size, void* d_ws, size_t ws_size,
                              hipStream_t stream) {
    const float* x    = (const float*)d_in[0];
    const float* Wih  = (const float*)d_in[1];
    const float* Whh  = (const float*)d_in[2];
    const float* bih  = (const float*)d_in[3];
    const float* bhh  = (const float*)d_in[4];
    float* y = (float*)d_out;

    char* ws = (char*)d_ws;
    size_t off = 0;
    auto alloc = [&](size_t bytes) { size_t p = off; off += (bytes + 255) & ~(size_t)255; return p; };

    unsigned* slots = (unsigned*)(ws + alloc(4 * 64 * 4));              // [4][64]
    u16* xb    = (u16*)(ws + alloc((size_t)T_SEQ * BATCH * IN_F * 2));  // 64 MB
    u16* wihb  = (u16*)(ws + alloc((size_t)G4 * IN_F * 2));             // 8 MB
    u16* whhb  = (u16*)(ws + alloc((size_t)G4 * HID_F * 2));            // 8 MB
    u64* hbuf0 = (u64*)(ws + alloc((size_t)BATCH * 256 * 8));           // 128 KB
    u64* hbuf1 = (u64*)(ws + alloc((size_t)BATCH * 256 * 8));           // 128 KB

    cast_bf16_k<<<2048, 256, 0, stream>>>(x,   xb,   (long)T_SEQ * BATCH * IN_F / 4);
    cast_bf16_k<<<512,  256, 0, stream>>>(Wih, wihb, (long)G4 * IN_F / 4);
    cast_bf16_k<<<512,  256, 0, stream>>>(Whh, whhb, (long)G4 * HID_F / 4);

    hipMemsetAsync(slots, 0, 4 * 64 * 4, stream);
    hipMemsetAsync(hbuf0, 0, (size_t)BATCH * 256 * 8, stream);   // h(0) = 0

    lstm_seq_k<<<256, 256, 0, stream>>>(whhb, wihb, xb, hbuf0, hbuf1, bih, bhh, y, slots);
}